// Round 4
// baseline (158.413 us; speedup 1.0000x reference)
//
#include <hip/hip_runtime.h>
#include <math.h>

#define D 256            // feature dim: one row = 1 KB = one wave64 float4 load
#define NBLOCKS 4096
#define WAVES 4          // 256-thread blocks
#define ROUNDS 2         // 4096 blocks * 4 waves * 2 nodes * 2 rounds = 65536 nodes

// softplus(-p) = max(-p,0) + log(1+exp(-|p|)); fast intrinsics fine:
// threshold is 135 absolute on a ~6752 output (2%).
__device__ __forceinline__ float spn(float p) {
    return fmaxf(-p, 0.0f) + __logf(1.0f + __expf(-fabsf(p)));
}

__device__ __forceinline__ float dot4(float4 a, float4 b) {
    return a.x * b.x + a.y * b.y + a.z * b.z + a.w * b.w;
}

// Full 64-lane reduction, VALU-only (DPP). Result valid in lane 63.
__device__ __forceinline__ float wave64_reduce(float x) {
    int t;
    t = __builtin_amdgcn_update_dpp(0, __builtin_bit_cast(int, x), 0x111, 0xf, 0xf, true);
    x += __builtin_bit_cast(float, t);
    t = __builtin_amdgcn_update_dpp(0, __builtin_bit_cast(int, x), 0x112, 0xf, 0xf, true);
    x += __builtin_bit_cast(float, t);
    t = __builtin_amdgcn_update_dpp(0, __builtin_bit_cast(int, x), 0x114, 0xf, 0xf, true);
    x += __builtin_bit_cast(float, t);
    t = __builtin_amdgcn_update_dpp(0, __builtin_bit_cast(int, x), 0x118, 0xf, 0xf, true);
    x += __builtin_bit_cast(float, t);
    t = __builtin_amdgcn_update_dpp(0, __builtin_bit_cast(int, x), 0x142, 0xa, 0xf, true); // row_bcast15
    x += __builtin_bit_cast(float, t);
    t = __builtin_amdgcn_update_dpp(0, __builtin_bit_cast(int, x), 0x143, 0xc, 0xf, true); // row_bcast31
    x += __builtin_bit_cast(float, t);
    return x;   // lane 63 holds the full sum
}

// Stage one 1 KB row (64 lanes x 16 B) global -> LDS with NO destination
// registers: the register allocator cannot serialize what it cannot see.
// Global src is per-lane; LDS dst is wave-uniform base + lane*16 (m97 rule).
__device__ __forceinline__ void stage_row(const float* grow, float* ldsrow, int lane) {
    __builtin_amdgcn_global_load_lds(
        (const __attribute__((address_space(1))) void*)((const float4*)grow + lane),
        (__attribute__((address_space(3))) void*)ldsrow,
        16, 0, 0);
}

// R0-R3 lesson: every structure where load destinations are VGPRs ends up
// serialized by the toolchain to ~4 live dests (VGPR_Count pinned at 28-32;
// wave lifetime == 12 sequential ~1000cy round-trips; 43us at 20% HBM, and
// the serialized model reproduces the time exactly). global_load_lds is
// dest-register-free, so all 12 row loads per wave are provably in flight
// until our single manual vmcnt(0). LDS slice is wave-private -> no barrier.
__global__ __launch_bounds__(256) void jsd_dot_stage_kernel(
    const int*   __restrict__ b1,
    const int*   __restrict__ b2,
    const float* __restrict__ z1,
    const float* __restrict__ z2,
    const float* __restrict__ g1,
    const float* __restrict__ g2,
    float*       __restrict__ partials)   // [NBLOCKS*2]
{
    // 12 rows/wave * 4 waves * 1 KB = 48 KB -> 3 blocks/CU (144/160 KB).
    __shared__ float lds[WAVES * 12 * D];
    __shared__ float s1[WAVES], s2[WAVES];

    const int wave = threadIdx.x >> 6;
    const int lane = threadIdx.x & 63;
    float* const slice = lds + wave * 12 * D;

    // First node index this wave handles in round 0 (wave-uniform -> s_load
    // addressing for b1/b2 and SGPR base for z rows).
    const int nb0 = __builtin_amdgcn_readfirstlane(blockIdx.x * (WAVES * 2 * ROUNDS) + wave * 2);

    float acc1 = 0.0f, acc2 = 0.0f;

    #pragma unroll
    for (int r = 0; r < ROUNDS; ++r) {
        const int n0 = nb0 + r * (WAVES * 2);   // this round's first node
        const int n1 = n0 + 1;

        // z rows first: addresses are index-independent, they fly while the
        // b1/b2 scalar loads resolve.
        stage_row(z1 + (size_t)n0 * D, slice + 0 * D, lane);
        stage_row(z2 + (size_t)n0 * D, slice + 1 * D, lane);
        stage_row(z1 + (size_t)n1 * D, slice + 6 * D, lane);
        stage_row(z2 + (size_t)n1 * D, slice + 7 * D, lane);

        const int i1_0 = b1[n0];
        const int i1_1 = b1[n1];
        const int i2_0 = b2[n0];
        const int i2_1 = b2[n1];

        // 8 g rows (g1/g2 ~1 MB total: L2-resident after first touch).
        stage_row(g1 + (size_t)i1_0 * D, slice + 2 * D, lane);
        stage_row(g2 + (size_t)i1_0 * D, slice + 3 * D, lane);
        stage_row(g2 + (size_t)i2_0 * D, slice + 4 * D, lane);
        stage_row(g1 + (size_t)i2_0 * D, slice + 5 * D, lane);
        stage_row(g1 + (size_t)i1_1 * D, slice + 8 * D, lane);
        stage_row(g2 + (size_t)i1_1 * D, slice + 9 * D, lane);
        stage_row(g2 + (size_t)i2_1 * D, slice + 10 * D, lane);
        stage_row(g1 + (size_t)i2_1 * D, slice + 11 * D, lane);

        // One drain for all 12 in-flight stages. sched_barrier stops any
        // consumer being hoisted above the wait (rule #18).
        asm volatile("s_waitcnt vmcnt(0)" ::: "memory");
        __builtin_amdgcn_sched_barrier(0);

        // node 0
        {
            const float4 a1  = ((const float4*)(slice + 0 * D))[lane];
            const float4 a2  = ((const float4*)(slice + 1 * D))[lane];
            const float4 w11 = ((const float4*)(slice + 2 * D))[lane];
            const float4 w12 = ((const float4*)(slice + 3 * D))[lane];
            const float4 w22 = ((const float4*)(slice + 4 * D))[lane];
            const float4 w21 = ((const float4*)(slice + 5 * D))[lane];
            float s11 = wave64_reduce(dot4(a1, w11));
            float c12 = wave64_reduce(dot4(a1, w12));
            float s22 = wave64_reduce(dot4(a2, w22));
            float c21 = wave64_reduce(dot4(a2, w21));
            if (lane == 63) {
                float d1 = spn(c12) - spn(s11);   // f(s)-f(c) = softplus(-c)-softplus(-s)
                float d2 = spn(c21) - spn(s22);
                acc1 += d1 * d1;
                acc2 += d2 * d2;
            }
        }
        // node 1
        {
            const float4 a1  = ((const float4*)(slice + 6 * D))[lane];
            const float4 a2  = ((const float4*)(slice + 7 * D))[lane];
            const float4 w11 = ((const float4*)(slice + 8 * D))[lane];
            const float4 w12 = ((const float4*)(slice + 9 * D))[lane];
            const float4 w22 = ((const float4*)(slice + 10 * D))[lane];
            const float4 w21 = ((const float4*)(slice + 11 * D))[lane];
            float s11 = wave64_reduce(dot4(a1, w11));
            float c12 = wave64_reduce(dot4(a1, w12));
            float s22 = wave64_reduce(dot4(a2, w22));
            float c21 = wave64_reduce(dot4(a2, w21));
            if (lane == 63) {
                float d1 = spn(c12) - spn(s11);
                float d2 = spn(c21) - spn(s22);
                acc1 += d1 * d1;
                acc2 += d2 * d2;
            }
        }

        // All LDS reads must complete before next round's stages overwrite
        // this slice (global_load_lds writes are async at data-return time).
        asm volatile("s_waitcnt lgkmcnt(0)" ::: "memory");
        __builtin_amdgcn_sched_barrier(0);
    }

    if (lane == 63) { s1[wave] = acc1; s2[wave] = acc2; }
    __syncthreads();

    if (threadIdx.x == 0) {
        float t1 = 0.0f, t2 = 0.0f;
        #pragma unroll
        for (int k = 0; k < WAVES; ++k) { t1 += s1[k]; t2 += s2[k]; }
        partials[blockIdx.x * 2 + 0] = t1;
        partials[blockIdx.x * 2 + 1] = t2;
    }
}

__global__ __launch_bounds__(256) void jsd_reduce_kernel(
    const float* __restrict__ partials,
    float*       __restrict__ out)
{
    const int tid  = threadIdx.x;
    const int wave = tid >> 6;
    const int lane = tid & 63;

    float a = 0.0f, b = 0.0f;
    #pragma unroll
    for (int i = 0; i < NBLOCKS / 256; ++i) {
        a += partials[(i * 256 + tid) * 2 + 0];
        b += partials[(i * 256 + tid) * 2 + 1];
    }

    a = wave64_reduce(a);
    b = wave64_reduce(b);

    __shared__ float s1[4], s2[4];
    if (lane == 63) { s1[wave] = a; s2[wave] = b; }
    __syncthreads();

    if (tid == 0) {
        float t1 = s1[0] + s1[1] + s1[2] + s1[3];
        float t2 = s2[0] + s2[1] + s2[2] + s2[3];
        out[0] = sqrtf(t1) + sqrtf(t2);
    }
}

extern "C" void kernel_launch(void* const* d_in, const int* in_sizes, int n_in,
                              void* d_out, int out_size, void* d_ws, size_t ws_size,
                              hipStream_t stream) {
    const int*   b1 = (const int*)  d_in[0];
    const int*   b2 = (const int*)  d_in[1];
    const float* z1 = (const float*)d_in[2];
    const float* z2 = (const float*)d_in[3];
    const float* g1 = (const float*)d_in[4];
    const float* g2 = (const float*)d_in[5];
    float* out      = (float*)d_out;
    float* partials = (float*)d_ws;   // NBLOCKS*2 floats, fully overwritten

    jsd_dot_stage_kernel<<<NBLOCKS, 256, 0, stream>>>(b1, b2, z1, z2, g1, g2, partials);
    jsd_reduce_kernel<<<1, 256, 0, stream>>>(partials, out);
}